// Round 1
// baseline (2863.024 us; speedup 1.0000x reference)
//
#include <hip/hip_runtime.h>
#include <cstddef>

// Problem constants
#define NWIN   1024     // B_ : number of windows
#define NTOK   64       // tokens per window (8x8)
#define CDIM   512      // DIM == INNER
#define NHEAD  16
#define HDIM   32

// ---------------------------------------------------------------------------
// Kernel 1: depthwise 3x3 (pad 1) + bias + ReLU, per 8x8 window.
// x: [NWIN][NTOK][CDIM] (fp32), dww: [CDIM][9], dwb: [CDIM]
// R: [NWIN*NTOK][CDIM]
// One block per window; channels processed in 4 tiles of 128.
// ---------------------------------------------------------------------------
__global__ __launch_bounds__(256) void dwrelu_kernel(
    const float* __restrict__ x, const float* __restrict__ dww,
    const float* __restrict__ dwb, float* __restrict__ R)
{
    __shared__ float xs[64][128];   // [token][channel-in-tile]
    const int b  = blockIdx.x;
    const int t  = threadIdx.x;
    const int cc = t & 127;         // channel within tile
    const int g  = t >> 7;          // token half (0/1)
    const float* xb = x + (size_t)b * NTOK * CDIM;

    for (int ct = 0; ct < 4; ++ct) {
        const int c0 = ct * 128;
        __syncthreads();            // previous tile's reads done
        // stage x[b][:, c0..c0+128) into LDS (coalesced)
        for (int r = 0; r < 32; ++r) {
            int idx = r * 256 + t;
            int n = idx >> 7, c = idx & 127;
            xs[n][c] = xb[(size_t)n * CDIM + c0 + c];
        }
        __syncthreads();
        float w[9];
        #pragma unroll
        for (int tap = 0; tap < 9; ++tap) w[tap] = dww[(size_t)(c0 + cc) * 9 + tap];
        const float bias = dwb[c0 + cc];

        for (int nn = 0; nn < 32; ++nn) {
            const int n = g * 32 + nn;
            const int i = n >> 3, j = n & 7;
            float acc = bias;
            #pragma unroll
            for (int di = 0; di < 3; ++di) {
                const int ii = i + di - 1;
                if (ii < 0 || ii >= 8) continue;
                #pragma unroll
                for (int dj = 0; dj < 3; ++dj) {
                    const int jj = j + dj - 1;
                    if (jj < 0 || jj >= 8) continue;
                    acc = fmaf(xs[ii * 8 + jj][cc], w[di * 3 + dj], acc);
                }
            }
            R[((size_t)b * NTOK + n) * CDIM + c0 + cc] = fmaxf(acc, 0.0f);
        }
    }
}

// ---------------------------------------------------------------------------
// Kernel 2: fp32 GEMM, C[M][512] = A[M][512] @ W[512][512]^T + bias
// (both row-major, "NT" layout). Block tile 64x64, 4x4 micro-tile, K-chunk 16.
// grid = (M/64, 512/64), block = 256.
// ---------------------------------------------------------------------------
__global__ __launch_bounds__(256) void gemm_nt(
    const float* __restrict__ A, const float* __restrict__ W,
    const float* __restrict__ bias, float* __restrict__ C)
{
    // pad 68 floats: 272 B row stride -> multiple of 16 B (float4 LDS reads ok)
    __shared__ float As[16][68];
    __shared__ float Ws[16][68];
    const int t  = threadIdx.x;
    const int bm = blockIdx.x * 64;
    const int bo = blockIdx.y * 64;
    const int tx = t & 15, ty = t >> 4;   // micro-tile coords
    const int lr = t >> 2;                // load row 0..63
    const int lk = (t & 3) * 4;           // load k offset {0,4,8,12}

    float acc[4][4] = {};
    const float* Ap = A + (size_t)(bm + lr) * 512 + lk;
    const float* Wp = W + (size_t)(bo + lr) * 512 + lk;

    for (int k0 = 0; k0 < 512; k0 += 16) {
        const float4 a4 = *(const float4*)(Ap + k0);
        const float4 w4 = *(const float4*)(Wp + k0);
        __syncthreads();   // previous compute done before overwriting LDS
        As[lk + 0][lr] = a4.x; As[lk + 1][lr] = a4.y;
        As[lk + 2][lr] = a4.z; As[lk + 3][lr] = a4.w;
        Ws[lk + 0][lr] = w4.x; Ws[lk + 1][lr] = w4.y;
        Ws[lk + 2][lr] = w4.z; Ws[lk + 3][lr] = w4.w;
        __syncthreads();
        #pragma unroll
        for (int kk = 0; kk < 16; ++kk) {
            const float4 av = *(const float4*)&As[kk][ty * 4];
            const float4 wv = *(const float4*)&Ws[kk][tx * 4];
            const float am[4] = {av.x, av.y, av.z, av.w};
            const float wm[4] = {wv.x, wv.y, wv.z, wv.w};
            #pragma unroll
            for (int i2 = 0; i2 < 4; ++i2)
                #pragma unroll
                for (int j2 = 0; j2 < 4; ++j2)
                    acc[i2][j2] = fmaf(am[i2], wm[j2], acc[i2][j2]);
        }
    }

    const float4 bb = *(const float4*)(bias + bo + tx * 4);
    const float bv[4] = {bb.x, bb.y, bb.z, bb.w};
    #pragma unroll
    for (int i2 = 0; i2 < 4; ++i2) {
        float4 o;
        o.x = acc[i2][0] + bv[0]; o.y = acc[i2][1] + bv[1];
        o.z = acc[i2][2] + bv[2]; o.w = acc[i2][3] + bv[3];
        *(float4*)(C + (size_t)(bm + ty * 4 + i2) * 512 + bo + tx * 4) = o;
    }
}

// ---------------------------------------------------------------------------
// Kernel 3: attention per (window b, head h).
// Q/K/V: [NWIN*NTOK][CDIM] with head h occupying cols h*32..h*32+31.
// S = scale*Q K^T + pos + mask[b]; softmax rows; O = S @ V -> AO same layout.
// grid = (NWIN, NHEAD), block = 256.
// ---------------------------------------------------------------------------
__global__ __launch_bounds__(256) void attn_kernel(
    const float* __restrict__ Q, const float* __restrict__ K,
    const float* __restrict__ V, const float* __restrict__ mask,
    const float* __restrict__ pos, float* __restrict__ AO)
{
    __shared__ float Qs[64][36], Ks[64][36], Vs[64][36]; // pad 36: 16B-aligned rows
    __shared__ float Ss[64][65];
    const int b = blockIdx.x, h = blockIdx.y;
    const int t = threadIdx.x;
    const int n  = t >> 2;          // this thread's row (0..63)
    const int d0 = (t & 3) * 8;     // 8-wide d slice
    const size_t base = ((size_t)b * NTOK) * CDIM + h * HDIM;

    { // load Q/K/V head tiles: each thread 8 contiguous floats per tensor
        const float* qp = Q + base + (size_t)n * CDIM + d0;
        const float* kp = K + base + (size_t)n * CDIM + d0;
        const float* vp = V + base + (size_t)n * CDIM + d0;
        *(float4*)&Qs[n][d0]     = *(const float4*)(qp);
        *(float4*)&Qs[n][d0 + 4] = *(const float4*)(qp + 4);
        *(float4*)&Ks[n][d0]     = *(const float4*)(kp);
        *(float4*)&Ks[n][d0 + 4] = *(const float4*)(kp + 4);
        *(float4*)&Vs[n][d0]     = *(const float4*)(vp);
        *(float4*)&Vs[n][d0 + 4] = *(const float4*)(vp + 4);
    }
    __syncthreads();

    // S rows: thread handles row n, 16 columns starting at j0
    float qreg[32];
    #pragma unroll
    for (int d = 0; d < 32; d += 4) {
        const float4 qv = *(const float4*)&Qs[n][d];
        qreg[d] = qv.x; qreg[d + 1] = qv.y; qreg[d + 2] = qv.z; qreg[d + 3] = qv.w;
    }
    const float scale = 0.17677669529663687f;   // (512/16)^-0.5
    const int j0 = (t & 3) * 16;
    const float* maskb = mask + (size_t)b * (NTOK * NTOK) + n * NTOK;
    const float* posn  = pos + n * NTOK;
    for (int jj = 0; jj < 16; ++jj) {
        const int j = j0 + jj;
        float dot = 0.0f;
        #pragma unroll
        for (int d = 0; d < 32; ++d) dot = fmaf(qreg[d], Ks[j][d], dot);
        Ss[n][j] = dot * scale + posn[j] + maskb[j];
    }
    __syncthreads();

    // softmax: one lane per row
    if (t < 64) {
        float m = -1e30f;
        for (int j = 0; j < 64; ++j) m = fmaxf(m, Ss[t][j]);
        float s = 0.0f;
        for (int j = 0; j < 64; ++j) { const float e = __expf(Ss[t][j] - m); Ss[t][j] = e; s += e; }
        const float inv = 1.0f / s;
        for (int j = 0; j < 64; ++j) Ss[t][j] *= inv;
    }
    __syncthreads();

    // O = S @ V : thread computes row n, cols d0..d0+7
    float o[8] = {};
    for (int j = 0; j < 64; ++j) {
        const float s = Ss[n][j];
        #pragma unroll
        for (int dd = 0; dd < 8; ++dd) o[dd] = fmaf(s, Vs[j][d0 + dd], o[dd]);
    }
    float4 o0, o1;
    o0.x = o[0]; o0.y = o[1]; o0.z = o[2]; o0.w = o[3];
    o1.x = o[4]; o1.y = o[5]; o1.z = o[6]; o1.w = o[7];
    *(float4*)(AO + base + (size_t)n * CDIM + d0)     = o0;
    *(float4*)(AO + base + (size_t)n * CDIM + d0 + 4) = o1;
}

// ---------------------------------------------------------------------------
// Launch: dw(q)->R, pw(q)->Q, dw(k)->R, pw(k)->K, dw(v)->R, pw(v)->V,
// attn->AO (reuses R), proj->out.  ws usage: 4 x 128 MiB = 512 MiB.
// ---------------------------------------------------------------------------
extern "C" void kernel_launch(void* const* d_in, const int* in_sizes, int n_in,
                              void* d_out, int out_size, void* d_ws, size_t ws_size,
                              hipStream_t stream) {
    const float* x      = (const float*)d_in[0];
    const float* mask   = (const float*)d_in[1];
    const float* dwq_w  = (const float*)d_in[2];
    const float* dwq_b  = (const float*)d_in[3];
    const float* pwq_w  = (const float*)d_in[4];
    const float* pwq_b  = (const float*)d_in[5];
    const float* dwk_w  = (const float*)d_in[6];
    const float* dwk_b  = (const float*)d_in[7];
    const float* pwk_w  = (const float*)d_in[8];
    const float* pwk_b  = (const float*)d_in[9];
    const float* dwv_w  = (const float*)d_in[10];
    const float* dwv_b  = (const float*)d_in[11];
    const float* pwv_w  = (const float*)d_in[12];
    const float* pwv_b  = (const float*)d_in[13];
    const float* pos    = (const float*)d_in[14];
    const float* proj_w = (const float*)d_in[15];
    const float* proj_b = (const float*)d_in[16];
    float* out = (float*)d_out;

    const size_t sz = (size_t)NWIN * NTOK * CDIM;   // 33,554,432 floats
    float* R  = (float*)d_ws;       // dw+relu staging; later reused as attn out
    float* Qb = R + sz;
    float* Kb = Qb + sz;
    float* Vb = Kb + sz;

    const dim3 blk(256);
    const dim3 gdw(NWIN);
    const dim3 ggm(NWIN * NTOK / 64, CDIM / 64);    // (1024, 8)
    const dim3 gat(NWIN, NHEAD);                    // (1024, 16)

    dwrelu_kernel<<<gdw, blk, 0, stream>>>(x, dwq_w, dwq_b, R);
    gemm_nt<<<ggm, blk, 0, stream>>>(R, pwq_w, pwq_b, Qb);
    dwrelu_kernel<<<gdw, blk, 0, stream>>>(x, dwk_w, dwk_b, R);
    gemm_nt<<<ggm, blk, 0, stream>>>(R, pwk_w, pwk_b, Kb);
    dwrelu_kernel<<<gdw, blk, 0, stream>>>(x, dwv_w, dwv_b, R);
    gemm_nt<<<ggm, blk, 0, stream>>>(R, pwv_w, pwv_b, Vb);
    attn_kernel<<<gat, blk, 0, stream>>>(Qb, Kb, Vb, mask, pos, R);
    gemm_nt<<<ggm, blk, 0, stream>>>(R, proj_w, proj_b, out);
}

// Round 2
// 1636.140 us; speedup vs baseline: 1.7499x; 1.7499x over previous
//
#include <hip/hip_runtime.h>
#include <cstddef>
#include <cstdint>

#define NWIN  1024
#define NTOK  64
#define CDIM  512
#define NHEAD 16
#define HDIM  32
#define MTOT  (NWIN * NTOK)   // 65536 rows

typedef __attribute__((ext_vector_type(8))) short short8;   // 8 bf16 = 4 VGPRs
typedef __attribute__((ext_vector_type(4))) float floatx4;  // MFMA acc

// trunc-split: f = hi + lo + eps, |eps| <= 2^-16 |f|
__device__ __forceinline__ void split_bf16(float f, unsigned short& hi, unsigned short& lo) {
    unsigned u = __float_as_uint(f);
    hi = (unsigned short)(u >> 16);
    float hf = __uint_as_float(u & 0xffff0000u);
    lo = (unsigned short)(__float_as_uint(f - hf) >> 16);
}

// ---------------------------------------------------------------------------
// depthwise 3x3 + bias + ReLU -> bf16 hi/lo planes.
// grid (NWIN, 4 channel-tiles), block 256.
// ---------------------------------------------------------------------------
__global__ __launch_bounds__(256) void dwrelu_kernel(
    const float* __restrict__ x, const float* __restrict__ dww,
    const float* __restrict__ dwb,
    unsigned short* __restrict__ Rh, unsigned short* __restrict__ Rl)
{
    __shared__ float xs[64][128];
    const int b = blockIdx.x, ct = blockIdx.y;
    const int t = threadIdx.x;
    const int c0 = ct * 128;
    const float* xb = x + (size_t)b * NTOK * CDIM + c0;

    #pragma unroll
    for (int r = 0; r < 8; ++r) {               // 2048 float4s / 256 threads
        int idx = r * 256 + t;
        int n = idx >> 5, c4 = (idx & 31) * 4;
        *(float4*)&xs[n][c4] = *(const float4*)(xb + (size_t)n * CDIM + c4);
    }
    __syncthreads();

    const int cc = t & 127, g = t >> 7;
    float w[9];
    #pragma unroll
    for (int tap = 0; tap < 9; ++tap) w[tap] = dww[(size_t)(c0 + cc) * 9 + tap];
    const float bias = dwb[c0 + cc];

    for (int nn = 0; nn < 32; ++nn) {
        const int n = g * 32 + nn;
        const int i = n >> 3, j = n & 7;
        float acc = bias;
        #pragma unroll
        for (int di = 0; di < 3; ++di) {
            const int ii = i + di - 1;
            if (ii < 0 || ii >= 8) continue;
            #pragma unroll
            for (int dj = 0; dj < 3; ++dj) {
                const int jj = j + dj - 1;
                if (jj < 0 || jj >= 8) continue;
                acc = fmaf(xs[ii * 8 + jj][cc], w[di * 3 + dj], acc);
            }
        }
        acc = fmaxf(acc, 0.0f);
        unsigned short h, l;
        split_bf16(acc, h, l);
        const size_t o = ((size_t)b * NTOK + n) * CDIM + c0 + cc;
        Rh[o] = h; Rl[o] = l;
    }
}

// ---------------------------------------------------------------------------
// Split-bf16 MFMA GEMM: C[M][512] = A @ W^T + bias, A given as hi/lo bf16
// planes, W fp32 (split inline). No LDS, no barriers: fragments straight
// from global (L2/L3 resident). Block 256 = 4 waves (2x2), tile 128x128,
// 4x4 16x16x32 tiles per wave, 3 MFMAs per tile (AhBh + AhBl + AlBh).
// ---------------------------------------------------------------------------
__global__ __launch_bounds__(256) void gemm_bb(
    const unsigned short* __restrict__ Ah, const unsigned short* __restrict__ Al,
    const float* __restrict__ W, const float* __restrict__ bias,
    float* __restrict__ C)
{
    const int t = threadIdx.x;
    const int wave = t >> 6, lane = t & 63;
    const int wr = wave >> 1, wc = wave & 1;
    const int q = lane >> 4, mr = lane & 15;
    const int bm = blockIdx.x * 128, bo = blockIdx.y * 128;

    const floatx4 zero = {0.f, 0.f, 0.f, 0.f};
    floatx4 acc[4][4];
    #pragma unroll
    for (int i = 0; i < 4; ++i)
        #pragma unroll
        for (int j = 0; j < 4; ++j) acc[i][j] = zero;

    size_t aoff[4], woff[4];
    #pragma unroll
    for (int i = 0; i < 4; ++i) {
        aoff[i] = (size_t)(bm + wr * 64 + i * 16 + mr) * CDIM;
        woff[i] = (size_t)(bo + wc * 64 + i * 16 + mr) * CDIM;
    }

    for (int k0 = 0; k0 < 512; k0 += 32) {
        const int kk = k0 + q * 8;
        short8 afh[4], afl[4], wfh[4], wfl[4];
        #pragma unroll
        for (int i = 0; i < 4; ++i) {
            afh[i] = *(const short8*)(Ah + aoff[i] + kk);
            afl[i] = *(const short8*)(Al + aoff[i] + kk);
        }
        #pragma unroll
        for (int j = 0; j < 4; ++j) {
            const float4 w0 = *(const float4*)(W + woff[j] + kk);
            const float4 w1 = *(const float4*)(W + woff[j] + kk + 4);
            const float wv[8] = {w0.x, w0.y, w0.z, w0.w, w1.x, w1.y, w1.z, w1.w};
            short8 h, l;
            #pragma unroll
            for (int e = 0; e < 8; ++e) {
                unsigned short hh, ll;
                split_bf16(wv[e], hh, ll);
                h[e] = (short)hh; l[e] = (short)ll;
            }
            wfh[j] = h; wfl[j] = l;
        }
        #pragma unroll
        for (int i = 0; i < 4; ++i)
            #pragma unroll
            for (int j = 0; j < 4; ++j) {
                acc[i][j] = __builtin_amdgcn_mfma_f32_16x16x32_bf16(afh[i], wfh[j], acc[i][j], 0, 0, 0);
                acc[i][j] = __builtin_amdgcn_mfma_f32_16x16x32_bf16(afh[i], wfl[j], acc[i][j], 0, 0, 0);
                acc[i][j] = __builtin_amdgcn_mfma_f32_16x16x32_bf16(afl[i], wfh[j], acc[i][j], 0, 0, 0);
            }
    }

    #pragma unroll
    for (int j = 0; j < 4; ++j) {
        const int col = bo + wc * 64 + j * 16 + mr;
        const float bv = bias[col];
        #pragma unroll
        for (int i = 0; i < 4; ++i) {
            const int row0 = bm + wr * 64 + i * 16 + q * 4;
            #pragma unroll
            for (int r = 0; r < 4; ++r)
                C[(size_t)(row0 + r) * CDIM + col] = acc[i][j][r] + bv;
        }
    }
}

// ---------------------------------------------------------------------------
// Attention per (window, head). Conflict-free LDS (Kt pad 68, Vs pad 36,
// Ss pad 65), Q in registers, parallel softmax. Output = bf16 hi/lo planes.
// grid (NWIN, NHEAD), block 256.
// ---------------------------------------------------------------------------
__global__ __launch_bounds__(256) void attn_kernel(
    const float* __restrict__ Q, const float* __restrict__ K,
    const float* __restrict__ V, const float* __restrict__ mask,
    const float* __restrict__ pos,
    unsigned short* __restrict__ AOh, unsigned short* __restrict__ AOl)
{
    __shared__ float Kt[32][68];   // transposed K: [d][token]
    __shared__ float Vs[64][36];
    __shared__ float Ss[64][65];
    const int b = blockIdx.x, h = blockIdx.y;
    const int t = threadIdx.x;
    const int n = t >> 2;              // token row (16 per wave, x4 groups)
    const int d0 = (t & 3) * 8;
    const size_t base = (size_t)b * NTOK * CDIM + h * HDIM;

    { // stage K (transposed) and V
        const float* kp = K + base + (size_t)n * CDIM + d0;
        const float4 k0v = *(const float4*)kp;
        const float4 k1v = *(const float4*)(kp + 4);
        Kt[d0 + 0][n] = k0v.x; Kt[d0 + 1][n] = k0v.y;
        Kt[d0 + 2][n] = k0v.z; Kt[d0 + 3][n] = k0v.w;
        Kt[d0 + 4][n] = k1v.x; Kt[d0 + 5][n] = k1v.y;
        Kt[d0 + 6][n] = k1v.z; Kt[d0 + 7][n] = k1v.w;
        const float* vp = V + base + (size_t)n * CDIM + d0;
        *(float4*)&Vs[n][d0]     = *(const float4*)vp;
        *(float4*)&Vs[n][d0 + 4] = *(const float4*)(vp + 4);
    }
    float qreg[32];
    {
        const float* qp = Q + base + (size_t)n * CDIM;
        #pragma unroll
        for (int c = 0; c < 8; ++c) {
            const float4 qv = *(const float4*)(qp + c * 4);
            qreg[c * 4] = qv.x; qreg[c * 4 + 1] = qv.y;
            qreg[c * 4 + 2] = qv.z; qreg[c * 4 + 3] = qv.w;
        }
    }
    __syncthreads();

    // S = scale*Q K^T + pos + mask  (thread: row n, cols j0..j0+15)
    const int j0 = (t & 3) * 16;
    float s[16];
    #pragma unroll
    for (int jj = 0; jj < 16; ++jj) s[jj] = 0.0f;
    for (int d = 0; d < 32; ++d) {
        const float qd = qreg[d];
        const float4 kt0 = *(const float4*)&Kt[d][j0];
        const float4 kt1 = *(const float4*)&Kt[d][j0 + 4];
        const float4 kt2 = *(const float4*)&Kt[d][j0 + 8];
        const float4 kt3 = *(const float4*)&Kt[d][j0 + 12];
        s[0]  = fmaf(qd, kt0.x, s[0]);  s[1]  = fmaf(qd, kt0.y, s[1]);
        s[2]  = fmaf(qd, kt0.z, s[2]);  s[3]  = fmaf(qd, kt0.w, s[3]);
        s[4]  = fmaf(qd, kt1.x, s[4]);  s[5]  = fmaf(qd, kt1.y, s[5]);
        s[6]  = fmaf(qd, kt1.z, s[6]);  s[7]  = fmaf(qd, kt1.w, s[7]);
        s[8]  = fmaf(qd, kt2.x, s[8]);  s[9]  = fmaf(qd, kt2.y, s[9]);
        s[10] = fmaf(qd, kt2.z, s[10]); s[11] = fmaf(qd, kt2.w, s[11]);
        s[12] = fmaf(qd, kt3.x, s[12]); s[13] = fmaf(qd, kt3.y, s[13]);
        s[14] = fmaf(qd, kt3.z, s[14]); s[15] = fmaf(qd, kt3.w, s[15]);
    }
    const float scale = 0.17677669529663687f;   // 32^-0.5
    const float* mrow = mask + (size_t)b * (NTOK * NTOK) + n * NTOK;
    const float* prow = pos + n * NTOK;
    #pragma unroll
    for (int jj = 0; jj < 16; ++jj)
        Ss[n][j0 + jj] = fmaf(s[jj], scale, prow[j0 + jj] + mrow[j0 + jj]);
    __syncthreads();

    // softmax: every thread computes stats for row r = t&63 (x4 redundant),
    // then wave g scales its 16-column block.
    const int r = t & 63, g = t >> 6;
    float mx = -1e30f;
    for (int j = 0; j < 64; ++j) mx = fmaxf(mx, Ss[r][j]);
    float sum = 0.0f;
    for (int j = 0; j < 64; ++j) sum += __expf(Ss[r][j] - mx);
    const float inv = 1.0f / sum;
    __syncthreads();                    // all raw-logit reads done
    #pragma unroll
    for (int jj = 0; jj < 16; ++jj) {
        const int j = g * 16 + jj;
        Ss[r][j] = __expf(Ss[r][j] - mx) * inv;
    }
    __syncthreads();

    // O = S @ V  (thread: row n, d0..d0+7)
    float o[8];
    #pragma unroll
    for (int dd = 0; dd < 8; ++dd) o[dd] = 0.0f;
    for (int j = 0; j < 64; ++j) {
        const float sv = Ss[n][j];
        const float4 v0 = *(const float4*)&Vs[j][d0];
        const float4 v1 = *(const float4*)&Vs[j][d0 + 4];
        o[0] = fmaf(sv, v0.x, o[0]); o[1] = fmaf(sv, v0.y, o[1]);
        o[2] = fmaf(sv, v0.z, o[2]); o[3] = fmaf(sv, v0.w, o[3]);
        o[4] = fmaf(sv, v1.x, o[4]); o[5] = fmaf(sv, v1.y, o[5]);
        o[6] = fmaf(sv, v1.z, o[6]); o[7] = fmaf(sv, v1.w, o[7]);
    }
    const size_t obase = base + (size_t)n * CDIM + d0;
    #pragma unroll
    for (int dd = 0; dd < 8; ++dd) {
        unsigned short hh, ll;
        split_bf16(o[dd], hh, ll);
        AOh[obase + dd] = hh;
        AOl[obase + dd] = ll;
    }
}

// ---------------------------------------------------------------------------
extern "C" void kernel_launch(void* const* d_in, const int* in_sizes, int n_in,
                              void* d_out, int out_size, void* d_ws, size_t ws_size,
                              hipStream_t stream) {
    const float* x      = (const float*)d_in[0];
    const float* mask   = (const float*)d_in[1];
    const float* dwq_w  = (const float*)d_in[2];
    const float* dwq_b  = (const float*)d_in[3];
    const float* pwq_w  = (const float*)d_in[4];
    const float* pwq_b  = (const float*)d_in[5];
    const float* dwk_w  = (const float*)d_in[6];
    const float* dwk_b  = (const float*)d_in[7];
    const float* pwk_w  = (const float*)d_in[8];
    const float* pwk_b  = (const float*)d_in[9];
    const float* dwv_w  = (const float*)d_in[10];
    const float* dwv_b  = (const float*)d_in[11];
    const float* pwv_w  = (const float*)d_in[12];
    const float* pwv_b  = (const float*)d_in[13];
    const float* pos    = (const float*)d_in[14];
    const float* proj_w = (const float*)d_in[15];
    const float* proj_b = (const float*)d_in[16];
    float* out = (float*)d_out;

    const size_t sz = (size_t)MTOT * CDIM;      // 33,554,432 elements
    // ws layout (512 MiB): [R: sz*4B = hi/lo ushort planes][Q fp32][K fp32][V fp32]
    unsigned short* Rh = (unsigned short*)d_ws;
    unsigned short* Rl = Rh + sz;
    float* Qb = (float*)d_ws + sz;
    float* Kb = Qb + sz;
    float* Vb = Kb + sz;
    // attention output planes reuse the (dead) R region
    unsigned short* AOh = Rh;
    unsigned short* AOl = Rl;

    const dim3 blk(256);
    const dim3 gdw(NWIN, 4);
    const dim3 ggm(MTOT / 128, CDIM / 128);     // (512, 4)
    const dim3 gat(NWIN, NHEAD);

    dwrelu_kernel<<<gdw, blk, 0, stream>>>(x, dwq_w, dwq_b, Rh, Rl);
    gemm_bb<<<ggm, blk, 0, stream>>>(Rh, Rl, pwq_w, pwq_b, Qb);
    dwrelu_kernel<<<gdw, blk, 0, stream>>>(x, dwk_w, dwk_b, Rh, Rl);
    gemm_bb<<<ggm, blk, 0, stream>>>(Rh, Rl, pwk_w, pwk_b, Kb);
    dwrelu_kernel<<<gdw, blk, 0, stream>>>(x, dwv_w, dwv_b, Rh, Rl);
    gemm_bb<<<ggm, blk, 0, stream>>>(Rh, Rl, pwv_w, pwv_b, Vb);
    attn_kernel<<<gat, blk, 0, stream>>>(Qb, Kb, Vb, mask, pos, AOh, AOl);
    gemm_bb<<<ggm, blk, 0, stream>>>(AOh, AOl, proj_w, proj_b, out);
}